// Round 6
// baseline (155.368 us; speedup 1.0000x reference)
//
#include <hip/hip_runtime.h>

// Problem constants (fixed by reference setup_inputs)
#define B_      64
#define K_      4
#define M_      3
#define NPIX    65536          // X*Y = 256*256
#define CHUNKS  8              // blocks per image -> grid 512 = 2 blocks/CU
#define TPB     256            // threads per block (4 waves)
#define SPAN    (NPIX / CHUNKS)       // 8192 px per block
#define TILE    1024           // px per stage
#define STAGES  (SPAN / TILE)  // 8
#define NV      16             // 4 den + 12 num partials per thread

// ---- async global->LDS, 16 B per lane ----
typedef __attribute__((address_space(1))) const void gas_t;
typedef __attribute__((address_space(3))) void las_t;
__device__ __forceinline__ void gload16(const void* g, void* l) {
    __builtin_amdgcn_global_load_lds((gas_t*)g, (las_t*)l, 16, 0, 0);
}

// Stream layout in an LDS stage buffer (floats): sid*TILE
//   sid 0     : heart (int bits)
//   sid 1..3  : inp m = sid-1
//   sid 4..7  : pred k = sid-4
// Wave w loads streams {2w, 2w+1}: per stream 4 sequential 1-KB wave-bursts.
// DRAM-visible pattern per wave = contiguous 4 KB bursts (vs. the 8-way
// interleaved pattern of R1-R5, all stuck at ~3.1 TB/s effective read).
__device__ __forceinline__ void load_stage(
    const float* __restrict__ pred_b, const float* __restrict__ inp_b,
    const int* __restrict__ heart_b, float* buf, int tile_px, int wv, int ln)
{
#pragma unroll
    for (int j = 0; j < 2; ++j) {
        const int sid = 2 * wv + j;           // wave-uniform
        const float* g;
        if (sid == 0)      g = (const float*)(heart_b + tile_px);
        else if (sid <= 3) g = inp_b  + (size_t)(sid - 1) * NPIX + tile_px;
        else               g = pred_b + (size_t)(sid - 4) * NPIX + tile_px;
        float* l = buf + sid * TILE;
#pragma unroll
        for (int i = 0; i < 4; ++i)           // 4 x 1 KB = 4 KB per stream
            gload16(g + i * 256 + ln * 4, l + i * 256);
    }
}

__global__ __launch_bounds__(TPB) void partial_kernel(
    const float* __restrict__ pred,    // [B,K,NPIX]
    const float* __restrict__ inp,     // [B,M,NPIX]
    const int*   __restrict__ heart,   // [B,NPIX]
    float* __restrict__ partial_ws)    // [B,CHUNKS,NV]
{
    const int c = blockIdx.x;          // chunk 0..CHUNKS-1
    const int b = blockIdx.y;          // image 0..63
    const int wv = threadIdx.x >> 6;
    const int ln = threadIdx.x & 63;
    const int t  = threadIdx.x;        // owns px [4t, 4t+4) of each tile

    const float* pred_b  = pred  + (size_t)b * K_ * NPIX;
    const float* inp_b   = inp   + (size_t)b * M_ * NPIX;
    const int*   heart_b = heart + (size_t)b * NPIX;
    const int base_px = c * SPAN;

    __shared__ float lds[2][8 * TILE];        // 2 x 32 KB
    __shared__ float smem[TPB / 64][NV];

    float val[NV];
#pragma unroll
    for (int i = 0; i < NV; ++i) val[i] = 0.0f;

    load_stage(pred_b, inp_b, heart_b, lds[0], base_px, wv, ln);

    for (int s = 0; s < STAGES; ++s) {
        // drains vmcnt (load s complete) + guards buffer reuse
        __syncthreads();
        if (s + 1 < STAGES)
            load_stage(pred_b, inp_b, heart_b, lds[(s + 1) & 1],
                       base_px + (s + 1) * TILE, wv, ln);

        const float* buf = lds[s & 1];
        const int4 h = reinterpret_cast<const int4*>(buf)[t];
        float4 mask;
        mask.x = (h.x == 1) ? 1.0f : 0.0f;
        mask.y = (h.y == 1) ? 1.0f : 0.0f;
        mask.z = (h.z == 1) ? 1.0f : 0.0f;
        mask.w = (h.w == 1) ? 1.0f : 0.0f;

        float4 in[M_];
#pragma unroll
        for (int m = 0; m < M_; ++m)
            in[m] = reinterpret_cast<const float4*>(buf + (1 + m) * TILE)[t];

#pragma unroll
        for (int k = 0; k < K_; ++k) {
            const float4 p = reinterpret_cast<const float4*>(buf + (4 + k) * TILE)[t];
            float4 pm;
            pm.x = p.x * mask.x; pm.y = p.y * mask.y;
            pm.z = p.z * mask.z; pm.w = p.w * mask.w;
            val[k] += (pm.x + pm.y) + (pm.z + pm.w);
#pragma unroll
            for (int m = 0; m < M_; ++m)
                val[4 + k * M_ + m] += pm.x * in[m].x + pm.y * in[m].y
                                     + pm.z * in[m].z + pm.w * in[m].w;
        }
    }

    // wave64 shuffle reduction (result lands on lane 0 of each wave)
#pragma unroll
    for (int off = 32; off > 0; off >>= 1) {
#pragma unroll
        for (int i = 0; i < NV; ++i)
            val[i] += __shfl_down(val[i], off, 64);
    }

    if (ln == 0) {
#pragma unroll
        for (int i = 0; i < NV; ++i) smem[wv][i] = val[i];
    }
    __syncthreads();

    if (t < NV) {
        const float s = smem[0][t] + smem[1][t] + smem[2][t] + smem[3][t];
        partial_ws[((size_t)b * CHUNKS + c) * NV + t] = s;
    }
}

// One wave: lane b owns image b; sum its chunk-partials, form ratios,
// reduce the 12 ratios over b, write the scalar.
__global__ __launch_bounds__(64) void finalize_kernel(
    const float* __restrict__ partial_ws,  // [B,CHUNKS,NV]
    const float* __restrict__ mu_data,     // [K,M]
    float* __restrict__ out)               // [1]
{
    const int b = threadIdx.x;  // 0..63 == B_
    float acc[NV];
#pragma unroll
    for (int i = 0; i < NV; ++i) acc[i] = 0.0f;
    for (int c = 0; c < CHUNKS; ++c) {
        const float* p = partial_ws + ((size_t)b * CHUNKS + c) * NV;
#pragma unroll
        for (int i = 0; i < NV; ++i) acc[i] += p[i];
    }

    float r[K_ * M_];
#pragma unroll
    for (int k = 0; k < K_; ++k) {
        const float inv = 1.0f / (acc[k] + 1e-10f);
#pragma unroll
        for (int m = 0; m < M_; ++m)
            r[k * M_ + m] = acc[4 + k * M_ + m] * inv;
    }
#pragma unroll
    for (int off = 32; off > 0; off >>= 1) {
#pragma unroll
        for (int i = 0; i < K_ * M_; ++i)
            r[i] += __shfl_down(r[i], off, 64);
    }
    if (b == 0) {
        float s = 0.0f;
#pragma unroll
        for (int i = 0; i < K_ * M_; ++i) {
            const float d = mu_data[i] - r[i] * (1.0f / (float)B_);
            s += d * d;
        }
        out[0] = s;
    }
}

extern "C" void kernel_launch(void* const* d_in, const int* in_sizes, int n_in,
                              void* d_out, int out_size, void* d_ws, size_t ws_size,
                              hipStream_t stream) {
    const float* pred    = (const float*)d_in[0];  // [64,4,256,256] f32
    const float* inp     = (const float*)d_in[1];  // [64,3,256,256] f32
    const int*   heart   = (const int*)d_in[2];    // [64,1,256,256] i32
    const float* mu_data = (const float*)d_in[3];  // [4,3] f32
    float* out = (float*)d_out;

    float* partial_ws = (float*)d_ws;  // [B][CHUNKS][NV] — fully written each call

    dim3 grid(CHUNKS, B_);
    partial_kernel<<<grid, TPB, 0, stream>>>(pred, inp, heart, partial_ws);
    finalize_kernel<<<1, 64, 0, stream>>>(partial_ws, mu_data, out);
}